// Round 7
// baseline (1569.654 us; speedup 1.0000x reference)
//
#include <hip/hip_runtime.h>
#include <hip/hip_bf16.h>

typedef unsigned short u16;
typedef unsigned int   u32;

#define V_N 100000
#define E_N 1600000
#define NIN 128
#define EIN 50
#define HH  50
#define TPB 8   // 64-edge tiles per block in k_edge; E_N = 3125 * 8 * 64 exactly

typedef __attribute__((ext_vector_type(8))) short bf16x8;
typedef __attribute__((ext_vector_type(4))) float f32x4;

__device__ __forceinline__ float bf2f(u16 u) {
    union { u32 i; float f; } v; v.i = ((u32)u) << 16; return v.f;
}
__device__ __forceinline__ u16 f2bf(float f) {
    union { float f; u32 i; } v; v.f = f;
    u32 x = v.i;
    return (u16)((x + 0x7fffu + ((x >> 16) & 1u)) >> 16);
}
// XOR swizzle on the element-in-row index (8-element/16B granules within each
// 128B sub-block). Verified on HW: k_edge SQ_LDS_BANK_CONFLICT ~800/block.
__device__ __forceinline__ int swz(int row, int k) { return k ^ ((row & 7) << 3); }

// ---------------------------------------------------------------------------
// Kernel A v3 (MFMA): C[64][112] = nf_tile[64][128] @ [w_l | w_r | 0]^T.
// v3: weight staging remapped so global reads are coalesced (n fast-varying);
// LDS writes become 8-way conflicting (cheap) instead of 64-way line splits.
// ---------------------------------------------------------------------------
__global__ __launch_bounds__(256, 3) void k_lr(
    const float* __restrict__ nf,
    const float* __restrict__ w1, const float* __restrict__ b1,
    const float* __restrict__ w2, const float* __restrict__ b2,
    u16* __restrict__ left, u16* __restrict__ right)
{
    __shared__ __align__(16) u16 sxa[64 * 128];    // nf tile, bf16, swizzled
    __shared__ __align__(16) u16 swt[112 * 128];   // [w_l|w_r]^T, bf16, swizzled
    __shared__ float sb[112];

    const int tid  = threadIdx.x;
    const int row0 = blockIdx.x * 64;

    const float4* nf4 = (const float4*)nf;
    for (int i = tid; i < 64 * 32; i += 256) {
        const int row = i >> 5, k4 = (i & 31) << 2;
        float4 v = make_float4(0.f, 0.f, 0.f, 0.f);
        const int gr = row0 + row;
        if (gr < V_N) v = nf4[(size_t)gr * 32 + (k4 >> 2)];
        ushort4 p;
        p.x = f2bf(v.x); p.y = f2bf(v.y); p.z = f2bf(v.z); p.w = f2bf(v.w);
        *(ushort4*)&sxa[(row << 7) + swz(row, k4)] = p;
    }
    // W^T staging, coalesced: consecutive lanes -> consecutive n
    for (int i = tid; i < 112 * 128; i += 256) {
        const int n = i % 112, k = i / 112;
        float v = 0.f;
        if (n < 50)       v = w1[k*50 + n];
        else if (n < 100) v = w2[k*50 + (n - 50)];
        swt[(n << 7) + swz(n, k)] = f2bf(v);
    }
    if (tid < 112)
        sb[tid] = (tid < 50) ? b1[tid] : (tid < 100 ? b2[tid - 50] : 0.f);
    __syncthreads();

    const int lane = tid & 63, wv = tid >> 6;
    const int frow = lane & 15;
    const int kofs = (lane >> 4) << 3;
    const int rbase = wv*16 + ((lane >> 4) << 2);
    const int arow  = wv*16 + frow;

    f32x4 zf = {0.f, 0.f, 0.f, 0.f};
    f32x4 acc[7];
    #pragma unroll
    for (int nt = 0; nt < 7; ++nt) acc[nt] = zf;

    #pragma unroll
    for (int kt = 0; kt < 4; ++kt) {
        bf16x8 a = *(const bf16x8*)&sxa[(arow << 7) + swz(arow, kt*32 + kofs)];
        #pragma unroll
        for (int nt = 0; nt < 7; ++nt) {
            const int nrow = nt*16 + frow;
            bf16x8 b = *(const bf16x8*)&swt[(nrow << 7) + swz(nrow, kt*32 + kofs)];
            acc[nt] = __builtin_amdgcn_mfma_f32_16x16x32_bf16(a, b, acc[nt], 0, 0, 0);
        }
    }
    #pragma unroll
    for (int nt = 0; nt < 7; ++nt) {
        const int g = nt*16 + frow;
        if (g < 100) {
            const float bias = sb[g];
            #pragma unroll
            for (int r = 0; r < 4; ++r) {
                const int gr = row0 + rbase + r;
                if (gr < V_N) {
                    const u16 o = f2bf(acc[nt][r] + bias);
                    if (g < 50) left [(size_t)gr*HH + g]      = o;
                    else        right[(size_t)gr*HH + g - 50] = o;
                }
            }
        }
    }
}

// ---------------------------------------------------------------------------
// Kernel B v3: structure = round-5-verified v2, plus:
//   - gather loads hoisted: 28 scattered ushort2 loads issued in ONE batch
//     into registers (statically-indexed unrolled arrays), then converted and
//     stored to LDS. Was ~7 serial load->wait->store round trips.
//   - stage-1 ef loads hoisted to 8 upfront float2 loads.
//   - wUt staging remapped for coalesced global reads.
// ---------------------------------------------------------------------------
__global__ __launch_bounds__(256, 3) void k_edge(
    const float* __restrict__ ef,
    const int* __restrict__ src, const int* __restrict__ dst,
    const float* __restrict__ wA, const float* __restrict__ bA,
    const float* __restrict__ wB, const float* __restrict__ bB,
    const float* __restrict__ wU, const float* __restrict__ bU,
    const u16* __restrict__ left, const u16* __restrict__ right,
    float* __restrict__ edge_node_acc,
    float* __restrict__ out_edge)
{
    __shared__ __align__(16) u16 sint[64 * 192];   // 24576 B
    __shared__ __align__(16) u16 wUt [64 * 192];   // 24576 B
    __shared__ float sb[3 * HH];                   // 600 B
    __shared__ int ssrc[64], sdst[64];             // 512 B

    const int tid  = threadIdx.x;
    const int lane = tid & 63, wv = tid >> 6;
    const int frow = lane & 15;
    const int kofs = (lane >> 4) << 3;             // 0,8,16,24
    const int rbase = wv*16 + ((lane >> 4) << 2);  // C rows: rbase + r
    const int arow  = wv*16 + frow;                // A row (edge-local)

    // ---- block-start staging (once) ----
    {
        uint4 z = make_uint4(0,0,0,0);
        for (int i = tid; i < 64*192/8; i += 256) ((uint4*)sint)[i] = z;
    }
    // wU^T staging, coalesced: consecutive lanes -> consecutive n (output col)
    for (int i = tid; i < 64*192; i += 256) {
        const int n = i & 63, kk = i >> 6;
        const int sec = kk >> 6, ko = kk & 63;
        u16 v = 0;
        if (n < 50 && ko < 50) v = f2bf(wU[(sec*50 + ko)*50 + n]);
        wUt[n*192 + swz(n, kk)] = v;
    }
    if (tid < 3*HH)
        sb[tid] = (tid < 50) ? bA[tid] : (tid < 100 ? bB[tid-50] : bU[tid-100]);

    // register B-fragments for stage 1 (W^T[n][k], n=nt*16+frow, k=kt*32+kofs+j)
    bf16x8 bAf[2][4], bBf[2][4];
    #pragma unroll
    for (int kt = 0; kt < 2; ++kt) {
        #pragma unroll
        for (int nt = 0; nt < 4; ++nt) {
            union { bf16x8 v; u16 u[8]; } r1, r2;
            const int n = nt*16 + frow;
            #pragma unroll
            for (int j = 0; j < 8; ++j) {
                const int k = kt*32 + kofs + j;
                float v1 = 0.f, v2 = 0.f;
                if (k < 50 && n < 50) { v1 = wA[k*50 + n]; v2 = wB[k*50 + n]; }
                r1.u[j] = f2bf(v1); r2.u[j] = f2bf(v2);
            }
            bAf[kt][nt] = r1.v; bBf[kt][nt] = r2.v;
        }
    }
    __syncthreads();

    for (int tile = 0; tile < TPB; ++tile) {
        const int e0t = blockIdx.x * (64*TPB) + tile*64;

        if (tid < 64) { ssrc[tid] = src[e0t+tid]; sdst[tid] = dst[e0t+tid]; }
        __syncthreads();   // (a) prev stage-2 done reading sint; ssrc visible

        // ---- gather loads: ALL issued in one batch into registers ----
        ushort2 gls[7], grd[7], grs[7], gld[7];
        #pragma unroll
        for (int it = 0; it < 7; ++it) {
            const int t = tid + it*256;
            if (t < 1600) {
                const int e = t / 25, q = t - e*25, c = q*2;
                const int s = ssrc[e], d = sdst[e];
                gls[it] = *(const ushort2*)&left [(size_t)s*HH + c];
                grd[it] = *(const ushort2*)&right[(size_t)d*HH + c];
                grs[it] = *(const ushort2*)&right[(size_t)s*HH + c];
                gld[it] = *(const ushort2*)&left [(size_t)d*HH + c];
            }
        }
        // ---- stage-1 ef loads: issued before gather stores ----
        const float* efr = ef + (size_t)(e0t + arow) * EIN;
        float2 ge2[8];
        #pragma unroll
        for (int kt = 0; kt < 2; ++kt) {
            #pragma unroll
            for (int p = 0; p < 4; ++p) {
                const int k = kt*32 + kofs + 2*p;
                float2 f = make_float2(0.f, 0.f);
                if (k < 50) f = *(const float2*)&efr[k];   // exec-masked, 8B-aligned
                ge2[kt*4 + p] = f;
            }
        }
        // ---- gather stores -> sint sections 0, 64 ----
        #pragma unroll
        for (int it = 0; it < 7; ++it) {
            const int t = tid + it*256;
            if (t < 1600) {
                const int e = t / 25, q = t - e*25, c = q*2;
                const u32 p1 = (u32)f2bf(fmaxf(bf2f(gls[it].x) + bf2f(grd[it].x), 0.f))
                             | ((u32)f2bf(fmaxf(bf2f(gls[it].y) + bf2f(grd[it].y), 0.f)) << 16);
                const u32 p2 = (u32)f2bf(fmaxf(bf2f(grs[it].x) + bf2f(gld[it].x), 0.f))
                             | ((u32)f2bf(fmaxf(bf2f(grs[it].y) + bf2f(gld[it].y), 0.f)) << 16);
                *(u32*)&sint[e*192 + swz(e, c)]      = p1;
                *(u32*)&sint[e*192 + swz(e, 64 + c)] = p2;
            }
        }

        // ---- stage 1: e2n (atomics) + third (-> sint section 128) ----
        {
            f32x4 zf = {0.f, 0.f, 0.f, 0.f};
            f32x4 accA[4], accB[4];
            #pragma unroll
            for (int nt = 0; nt < 4; ++nt) { accA[nt] = zf; accB[nt] = zf; }
            #pragma unroll
            for (int kt = 0; kt < 2; ++kt) {
                union { bf16x8 v; u16 u[8]; } a;
                #pragma unroll
                for (int p = 0; p < 4; ++p) {
                    const float2 f = ge2[kt*4 + p];
                    a.u[2*p]   = f2bf(f.x);
                    a.u[2*p+1] = f2bf(f.y);
                }
                #pragma unroll
                for (int nt = 0; nt < 4; ++nt) {
                    accA[nt] = __builtin_amdgcn_mfma_f32_16x16x32_bf16(a.v, bAf[kt][nt], accA[nt], 0, 0, 0);
                    accB[nt] = __builtin_amdgcn_mfma_f32_16x16x32_bf16(a.v, bBf[kt][nt], accB[nt], 0, 0, 0);
                }
            }
            #pragma unroll
            for (int nt = 0; nt < 4; ++nt) {
                const int c = nt*16 + frow;
                if (c < 50) {
                    const float ba = sb[c], bb = sb[HH + c];
                    #pragma unroll
                    for (int r = 0; r < 4; ++r) {
                        const int row = rbase + r;
                        const float v1 = fmaxf(accA[nt][r] + ba, 0.f);
                        atomicAdd(&edge_node_acc[(size_t)sdst[row]*HH + c], v1);
                        sint[row*192 + swz(row, 128 + c)] =
                            f2bf(fmaxf(accB[nt][r] + bb, 0.f));
                    }
                }
            }
        }
        __syncthreads();   // (b) sint fully written

        // ---- stage 2: new_edge = relu(sint @ wUt + bU) ----
        {
            f32x4 zf = {0.f, 0.f, 0.f, 0.f};
            f32x4 acc[4];
            #pragma unroll
            for (int nt = 0; nt < 4; ++nt) acc[nt] = zf;
            #pragma unroll
            for (int kt = 0; kt < 6; ++kt) {
                bf16x8 a = *(const bf16x8*)&sint[arow*192 + swz(arow, kt*32 + kofs)];
                #pragma unroll
                for (int nt = 0; nt < 4; ++nt) {
                    const int nrow = nt*16 + frow;
                    bf16x8 b = *(const bf16x8*)&wUt[nrow*192 + swz(nrow, kt*32 + kofs)];
                    acc[nt] = __builtin_amdgcn_mfma_f32_16x16x32_bf16(a, b, acc[nt], 0, 0, 0);
                }
            }
            #pragma unroll
            for (int nt = 0; nt < 4; ++nt) {
                const int c = nt*16 + frow;
                if (c < 50) {
                    const float bu = sb[2*HH + c];
                    #pragma unroll
                    for (int r = 0; r < 4; ++r) {
                        const int row = rbase + r;
                        out_edge[(size_t)(e0t + row)*HH + c] = fmaxf(acc[nt][r] + bu, 0.f);
                    }
                }
            }
        }
    }
}

// ---------------------------------------------------------------------------
// Kernel C v3 (MFMA): as round-6 verified, with weight staging remapped for
// coalesced global reads (n fast-varying).
// ---------------------------------------------------------------------------
__global__ __launch_bounds__(256, 2) void k_node_upd(
    const float* __restrict__ nf,
    const float* __restrict__ w_n2n, const float* __restrict__ b_n2n,
    const float* __restrict__ wU, const float* __restrict__ bU,
    float* __restrict__ node_out /* also edge_node accumulator */)
{
    __shared__ __align__(16) u16 smem[64*128 + 64*128];  // 32768 B
    __shared__ __align__(16) u16 swu[64 * 192];          // 24576 B
    __shared__ float sb[128];                            // b_n2n@0, bU@64

    const int tid = threadIdx.x;
    const int n0  = blockIdx.x * 64;

    const float4* nf4 = (const float4*)nf;
    for (int i = tid; i < 64 * 32; i += 256) {
        const int row = i >> 5, k4 = (i & 31) << 2;
        float4 v = make_float4(0.f, 0.f, 0.f, 0.f);
        const int gr = n0 + row;
        if (gr < V_N) v = nf4[(size_t)gr * 32 + (k4 >> 2)];
        ushort4 p;
        p.x = f2bf(v.x); p.y = f2bf(v.y); p.z = f2bf(v.z); p.w = f2bf(v.w);
        *(ushort4*)&smem[(row << 7) + swz(row, k4)] = p;
    }
    // w_n2n^T coalesced: consecutive lanes -> consecutive n
    for (int i = tid; i < 64 * 128; i += 256) {
        const int n = i & 63, k = i >> 6;
        const float v = (n < 50) ? w_n2n[k*50 + n] : 0.f;
        smem[8192 + (n << 7) + swz(n, k)] = f2bf(v);
    }
    // wU^T (sectioned) coalesced
    for (int i = tid; i < 64 * 192; i += 256) {
        const int n = i & 63, kk = i >> 6;
        float v = 0.f;
        if (n < 50) {
            if (kk < 100)      v = wU[kk*50 + n];
            else if (kk < 150) v = wU[(kk - 50)*50 + n];
        }
        swu[n*192 + swz(n, kk)] = f2bf(v);
    }
    if (tid < 128) {
        float v = 0.f;
        if (tid < 50) v = b_n2n[tid];
        else if (tid >= 64 && tid < 114) v = bU[tid - 64];
        sb[tid] = v;
    }
    __syncthreads();

    const int lane = tid & 63, wv = tid >> 6;
    const int frow = lane & 15;
    const int kofs = (lane >> 4) << 3;
    const int rbase = wv*16 + ((lane >> 4) << 2);
    const int arow  = wv*16 + frow;

    f32x4 zf = {0.f, 0.f, 0.f, 0.f};

    // ---- phase B: nn = nf @ w_n2n (bias+relu in epilogue) ----
    f32x4 accB[4];
    #pragma unroll
    for (int nt = 0; nt < 4; ++nt) accB[nt] = zf;
    #pragma unroll
    for (int kt = 0; kt < 4; ++kt) {
        bf16x8 a = *(const bf16x8*)&smem[(arow << 7) + swz(arow, kt*32 + kofs)];
        #pragma unroll
        for (int nt = 0; nt < 4; ++nt) {
            const int nrow = nt*16 + frow;
            bf16x8 b = *(const bf16x8*)&smem[8192 + (nrow << 7) + swz(nrow, kt*32 + kofs)];
            accB[nt] = __builtin_amdgcn_mfma_f32_16x16x32_bf16(a, b, accB[nt], 0, 0, 0);
        }
    }
    __syncthreads();   // all phase-B reads of smem complete

    // ---- build concat tile in smem[0..12288): [64][192] swizzled ----
    #pragma unroll
    for (int nt = 0; nt < 4; ++nt) {
        const int g = nt*16 + frow;
        if (g < 50) {
            const float bias = sb[g];
            #pragma unroll
            for (int r = 0; r < 4; ++r) {
                const int row = rbase + r;
                smem[row*192 + swz(row, g)] = f2bf(fmaxf(accB[nt][r] + bias, 0.f));
            }
        }
    }
    for (int i = tid; i < 4096; i += 256) {
        const int row = i >> 6, q = i & 63;
        if (q < 50) {
            float en = 0.f;
            const int gr = n0 + row;
            if (gr < V_N) en = node_out[(size_t)gr*HH + q];
            const u16 hi = f2bf(en);
            const u16 lo = f2bf(en - bf2f(hi));
            smem[row*192 + swz(row,  50 + q)] = hi;
            smem[row*192 + swz(row, 100 + q)] = lo;
        }
    }
    for (int i = tid; i < 4096; i += 256) {
        const int row = i >> 6, q = i & 63;
        if (q < 42) smem[row*192 + swz(row, 150 + q)] = 0;
    }
    __syncthreads();

    // ---- phase C: new_node = relu(concat @ swu + bU) ----
    f32x4 accC[4];
    #pragma unroll
    for (int nt = 0; nt < 4; ++nt) accC[nt] = zf;
    #pragma unroll
    for (int kt = 0; kt < 6; ++kt) {
        bf16x8 a = *(const bf16x8*)&smem[arow*192 + swz(arow, kt*32 + kofs)];
        #pragma unroll
        for (int nt = 0; nt < 4; ++nt) {
            const int nrow = nt*16 + frow;
            bf16x8 b = *(const bf16x8*)&swu[nrow*192 + swz(nrow, kt*32 + kofs)];
            accC[nt] = __builtin_amdgcn_mfma_f32_16x16x32_bf16(a, b, accC[nt], 0, 0, 0);
        }
    }
    #pragma unroll
    for (int nt = 0; nt < 4; ++nt) {
        const int g = nt*16 + frow;
        if (g < 50) {
            const float bias = sb[64 + g];
            #pragma unroll
            for (int r = 0; r < 4; ++r) {
                const int gr = n0 + rbase + r;
                if (gr < V_N)
                    node_out[(size_t)gr*HH + g] = fmaxf(accC[nt][r] + bias, 0.f);
            }
        }
    }
}

extern "C" void kernel_launch(void* const* d_in, const int* in_sizes, int n_in,
                              void* d_out, int out_size, void* d_ws, size_t ws_size,
                              hipStream_t stream) {
    const float* nf    = (const float*)d_in[0];
    const float* ef    = (const float*)d_in[1];
    const int*   src   = (const int*)d_in[2];
    const int*   dst   = (const int*)d_in[3];
    const float* w_n2n = (const float*)d_in[4];  const float* b_n2n = (const float*)d_in[5];
    const float* w_e2n = (const float*)d_in[6];  const float* b_e2n = (const float*)d_in[7];
    const float* w_updn= (const float*)d_in[8];  const float* b_updn= (const float*)d_in[9];
    const float* w_l   = (const float*)d_in[10]; const float* b_l   = (const float*)d_in[11];
    const float* w_r   = (const float*)d_in[12]; const float* b_r   = (const float*)d_in[13];
    const float* w_e2e = (const float*)d_in[14]; const float* b_e2e = (const float*)d_in[15];
    const float* w_upde= (const float*)d_in[16]; const float* b_upde= (const float*)d_in[17];

    // workspace layout: [0,10MB) left bf16 (V x 50), [10,20MB) right bf16
    char* ws = (char*)d_ws;
    u16* left  = (u16*)ws;
    u16* right = (u16*)(ws + 10000000);

    float* out_node = (float*)d_out;   // doubles as edge_node fp32 accumulator
    float* out_edge = out_node + (size_t)V_N * HH;

    hipMemsetAsync(out_node, 0, (size_t)V_N * HH * sizeof(float), stream);

    k_lr<<<(V_N + 63)/64, 256, 0, stream>>>(nf, w_l, b_l, w_r, b_r, left, right);

    k_edge<<<E_N/(64*TPB), 256, 0, stream>>>(
        ef, src, dst, w_e2n, b_e2n, w_e2e, b_e2e, w_upde, b_upde,
        left, right, out_node, out_edge);

    k_node_upd<<<(V_N + 63)/64, 256, 0, stream>>>(
        nf, w_n2n, b_n2n, w_updn, b_updn, out_node);
}

// Round 8
// 1287.325 us; speedup vs baseline: 1.2193x; 1.2193x over previous
//
#include <hip/hip_runtime.h>
#include <hip/hip_bf16.h>

typedef unsigned short u16;
typedef unsigned int   u32;

#define V_N 100000
#define E_N 1600000
#define NIN 128
#define EIN 50
#define HH  50
#define TPB 8   // 64-edge tiles per block in k_edge; E_N = 3125 * 8 * 64 exactly
#define NBLK 1563  // (V_N+63)/64

typedef __attribute__((ext_vector_type(8))) short bf16x8;
typedef __attribute__((ext_vector_type(4))) float f32x4;

__device__ __forceinline__ float bf2f(u16 u) {
    union { u32 i; float f; } v; v.i = ((u32)u) << 16; return v.f;
}
__device__ __forceinline__ u16 f2bf(float f) {
    union { float f; u32 i; } v; v.f = f;
    u32 x = v.i;
    return (u16)((x + 0x7fffu + ((x >> 16) & 1u)) >> 16);
}
// XOR swizzle on element-in-row index. NOTE (round-7 lesson): staging loops
// must keep the k/kk index FAST-VARYING across lanes (conflict-free LDS
// writes); n-fast "coalesced" variants create 64-way LDS write conflicts.
__device__ __forceinline__ int swz(int row, int k) { return k ^ ((row & 7) << 3); }

// ---------------------------------------------------------------------------
// Kernel A (round-6 verified): C[64][112] = nf[64][128] @ [w_l|w_r]^T.
// Fallback path (ws too small for nn buffer).
// ---------------------------------------------------------------------------
__global__ __launch_bounds__(256, 3) void k_lr(
    const float* __restrict__ nf,
    const float* __restrict__ w1, const float* __restrict__ b1,
    const float* __restrict__ w2, const float* __restrict__ b2,
    u16* __restrict__ left, u16* __restrict__ right)
{
    __shared__ __align__(16) u16 sxa[64 * 128];
    __shared__ __align__(16) u16 swt[112 * 128];
    __shared__ float sb[112];

    const int tid  = threadIdx.x;
    const int row0 = blockIdx.x * 64;

    const float4* nf4 = (const float4*)nf;
    for (int i = tid; i < 64 * 32; i += 256) {
        const int row = i >> 5, k4 = (i & 31) << 2;
        float4 v = make_float4(0.f, 0.f, 0.f, 0.f);
        const int gr = row0 + row;
        if (gr < V_N) v = nf4[(size_t)gr * 32 + (k4 >> 2)];
        ushort4 p;
        p.x = f2bf(v.x); p.y = f2bf(v.y); p.z = f2bf(v.z); p.w = f2bf(v.w);
        *(ushort4*)&sxa[(row << 7) + swz(row, k4)] = p;
    }
    for (int i = tid; i < 112 * 128; i += 256) {
        const int n = i >> 7, k = i & 127;   // k fast -> conflict-free LDS writes
        float v = 0.f;
        if (n < 50)       v = w1[k*50 + n];
        else if (n < 100) v = w2[k*50 + (n - 50)];
        swt[(n << 7) + swz(n, k)] = f2bf(v);
    }
    if (tid < 112)
        sb[tid] = (tid < 50) ? b1[tid] : (tid < 100 ? b2[tid - 50] : 0.f);
    __syncthreads();

    const int lane = tid & 63, wv = tid >> 6;
    const int frow = lane & 15;
    const int kofs = (lane >> 4) << 3;
    const int rbase = wv*16 + ((lane >> 4) << 2);
    const int arow  = wv*16 + frow;

    f32x4 zf = {0.f, 0.f, 0.f, 0.f};
    f32x4 acc[7];
    #pragma unroll
    for (int nt = 0; nt < 7; ++nt) acc[nt] = zf;

    #pragma unroll
    for (int kt = 0; kt < 4; ++kt) {
        bf16x8 a = *(const bf16x8*)&sxa[(arow << 7) + swz(arow, kt*32 + kofs)];
        #pragma unroll
        for (int nt = 0; nt < 7; ++nt) {
            const int nrow = nt*16 + frow;
            bf16x8 b = *(const bf16x8*)&swt[(nrow << 7) + swz(nrow, kt*32 + kofs)];
            acc[nt] = __builtin_amdgcn_mfma_f32_16x16x32_bf16(a, b, acc[nt], 0, 0, 0);
        }
    }
    #pragma unroll
    for (int nt = 0; nt < 7; ++nt) {
        const int g = nt*16 + frow;
        if (g < 100) {
            const float bias = sb[g];
            #pragma unroll
            for (int r = 0; r < 4; ++r) {
                const int gr = row0 + rbase + r;
                if (gr < V_N) {
                    const u16 o = f2bf(acc[nt][r] + bias);
                    if (g < 50) left [(size_t)gr*HH + g]      = o;
                    else        right[(size_t)gr*HH + g - 50] = o;
                }
            }
        }
    }
}

// ---------------------------------------------------------------------------
// Kernel A-fused: C[64][160] = nf[64][128] @ [w_l|w_r|w_n2n|0]^T.
// cols 0..49 left, 50..99 right (no relu), 100..149 nn = relu(.) -> ws.
// LDS 57984 B -> 2 blocks/CU.
// ---------------------------------------------------------------------------
__global__ __launch_bounds__(256, 2) void k_lr3(
    const float* __restrict__ nf,
    const float* __restrict__ w1, const float* __restrict__ b1,
    const float* __restrict__ w2, const float* __restrict__ b2,
    const float* __restrict__ wn, const float* __restrict__ bn,
    u16* __restrict__ left, u16* __restrict__ right, u16* __restrict__ nn)
{
    __shared__ __align__(16) u16 sxa[64 * 128];    // 16384 B
    __shared__ __align__(16) u16 swt[160 * 128];   // 40960 B
    __shared__ float sb[160];

    const int tid  = threadIdx.x;
    const int row0 = blockIdx.x * 64;

    const float4* nf4 = (const float4*)nf;
    for (int i = tid; i < 64 * 32; i += 256) {
        const int row = i >> 5, k4 = (i & 31) << 2;
        float4 v = make_float4(0.f, 0.f, 0.f, 0.f);
        const int gr = row0 + row;
        if (gr < V_N) v = nf4[(size_t)gr * 32 + (k4 >> 2)];
        ushort4 p;
        p.x = f2bf(v.x); p.y = f2bf(v.y); p.z = f2bf(v.z); p.w = f2bf(v.w);
        *(ushort4*)&sxa[(row << 7) + swz(row, k4)] = p;
    }
    for (int i = tid; i < 160 * 128; i += 256) {
        const int n = i >> 7, k = i & 127;   // k fast -> conflict-free LDS writes
        float v = 0.f;
        if (n < 50)       v = w1[k*50 + n];
        else if (n < 100) v = w2[k*50 + (n - 50)];
        else if (n < 150) v = wn[k*50 + (n - 100)];
        swt[(n << 7) + swz(n, k)] = f2bf(v);
    }
    if (tid < 160) {
        float v = 0.f;
        if (tid < 50)       v = b1[tid];
        else if (tid < 100) v = b2[tid - 50];
        else if (tid < 150) v = bn[tid - 100];
        sb[tid] = v;
    }
    __syncthreads();

    const int lane = tid & 63, wv = tid >> 6;
    const int frow = lane & 15;
    const int kofs = (lane >> 4) << 3;
    const int rbase = wv*16 + ((lane >> 4) << 2);
    const int arow  = wv*16 + frow;

    f32x4 zf = {0.f, 0.f, 0.f, 0.f};
    f32x4 acc[10];
    #pragma unroll
    for (int nt = 0; nt < 10; ++nt) acc[nt] = zf;

    #pragma unroll
    for (int kt = 0; kt < 4; ++kt) {
        bf16x8 a = *(const bf16x8*)&sxa[(arow << 7) + swz(arow, kt*32 + kofs)];
        #pragma unroll
        for (int nt = 0; nt < 10; ++nt) {
            const int nrow = nt*16 + frow;
            bf16x8 b = *(const bf16x8*)&swt[(nrow << 7) + swz(nrow, kt*32 + kofs)];
            acc[nt] = __builtin_amdgcn_mfma_f32_16x16x32_bf16(a, b, acc[nt], 0, 0, 0);
        }
    }
    #pragma unroll
    for (int nt = 0; nt < 10; ++nt) {
        const int g = nt*16 + frow;
        if (g < 150) {
            const float bias = sb[g];
            #pragma unroll
            for (int r = 0; r < 4; ++r) {
                const int gr = row0 + rbase + r;
                if (gr < V_N) {
                    const float s = acc[nt][r] + bias;
                    if (g < 50)       left [(size_t)gr*HH + g]       = f2bf(s);
                    else if (g < 100) right[(size_t)gr*HH + g - 50]  = f2bf(s);
                    else              nn   [(size_t)gr*HH + g - 100] = f2bf(fmaxf(s, 0.f));
                }
            }
        }
    }
}

// ---------------------------------------------------------------------------
// Kernel B v4 = round-6-verified v2 + ONE change: atomicAdds deferred past
// barrier (b), overlapping their vmcnt drain with stage-2 MFMA + next-tile
// gather. dst indices captured to registers BEFORE (b) (sdst is reloaded by
// the next tile between (b) and (a) -> LDS read after (b) would race).
// ---------------------------------------------------------------------------
__global__ __launch_bounds__(256, 3) void k_edge(
    const float* __restrict__ ef,
    const int* __restrict__ src, const int* __restrict__ dst,
    const float* __restrict__ wA, const float* __restrict__ bA,
    const float* __restrict__ wB, const float* __restrict__ bB,
    const float* __restrict__ wU, const float* __restrict__ bU,
    const u16* __restrict__ left, const u16* __restrict__ right,
    float* __restrict__ edge_node_acc,
    float* __restrict__ out_edge)
{
    __shared__ __align__(16) u16 sint[64 * 192];   // 24576 B
    __shared__ __align__(16) u16 wUt [64 * 192];   // 24576 B
    __shared__ float sb[3 * HH];                   // 600 B
    __shared__ int ssrc[64], sdst[64];             // 512 B

    const int tid  = threadIdx.x;
    const int lane = tid & 63, wv = tid >> 6;
    const int frow = lane & 15;
    const int kofs = (lane >> 4) << 3;             // 0,8,16,24
    const int rbase = wv*16 + ((lane >> 4) << 2);  // C rows: rbase + r
    const int arow  = wv*16 + frow;                // A row (edge-local)

    // ---- block-start staging (once) ----
    {
        uint4 z = make_uint4(0,0,0,0);
        for (int i = tid; i < 64*192/8; i += 256) ((uint4*)sint)[i] = z;
    }
    for (int i = tid; i < 64*192; i += 256) {      // round-6 mapping: kk fast
        const int c = i / 192, kk = i - c*192;
        const int sec = kk >> 6, ko = kk & 63;
        u16 v = 0;
        if (c < 50 && ko < 50) v = f2bf(wU[(sec*50 + ko)*50 + c]);
        wUt[c*192 + swz(c, kk)] = v;
    }
    if (tid < 3*HH)
        sb[tid] = (tid < 50) ? bA[tid] : (tid < 100 ? bB[tid-50] : bU[tid-100]);

    // register B-fragments for stage 1
    bf16x8 bAf[2][4], bBf[2][4];
    #pragma unroll
    for (int kt = 0; kt < 2; ++kt) {
        #pragma unroll
        for (int nt = 0; nt < 4; ++nt) {
            union { bf16x8 v; u16 u[8]; } r1, r2;
            const int n = nt*16 + frow;
            #pragma unroll
            for (int j = 0; j < 8; ++j) {
                const int k = kt*32 + kofs + j;
                float v1 = 0.f, v2 = 0.f;
                if (k < 50 && n < 50) { v1 = wA[k*50 + n]; v2 = wB[k*50 + n]; }
                r1.u[j] = f2bf(v1); r2.u[j] = f2bf(v2);
            }
            bAf[kt][nt] = r1.v; bBf[kt][nt] = r2.v;
        }
    }
    __syncthreads();

    for (int tile = 0; tile < TPB; ++tile) {
        const int e0t = blockIdx.x * (64*TPB) + tile*64;

        if (tid < 64) { ssrc[tid] = src[e0t+tid]; sdst[tid] = dst[e0t+tid]; }
        __syncthreads();   // (a) prev stage-2 done; prev atomics drained here

        // ---- gather: first/second -> sint sections 0, 64 (round-6 serial) ----
        for (int t = tid; t < 64*25; t += 256) {
            const int e = t / 25, q = t - e*25, c = q*2;
            const int s = ssrc[e], d = sdst[e];
            const ushort2 ls  = *(const ushort2*)&left [(size_t)s*HH + c];
            const ushort2 rd_ = *(const ushort2*)&right[(size_t)d*HH + c];
            const ushort2 rs  = *(const ushort2*)&right[(size_t)s*HH + c];
            const ushort2 ld  = *(const ushort2*)&left [(size_t)d*HH + c];
            const u32 p1 = (u32)f2bf(fmaxf(bf2f(ls.x) + bf2f(rd_.x), 0.f))
                         | ((u32)f2bf(fmaxf(bf2f(ls.y) + bf2f(rd_.y), 0.f)) << 16);
            const u32 p2 = (u32)f2bf(fmaxf(bf2f(rs.x) + bf2f(ld.x), 0.f))
                         | ((u32)f2bf(fmaxf(bf2f(rs.y) + bf2f(ld.y), 0.f)) << 16);
            *(u32*)&sint[e*192 + swz(e, c)]      = p1;
            *(u32*)&sint[e*192 + swz(e, 64 + c)] = p2;
        }

        // ---- stage 1: MFMA; sint writes now, atomics AFTER barrier (b) ----
        f32x4 accA[4];
        int rd_[4];
        {
            f32x4 zf = {0.f, 0.f, 0.f, 0.f};
            f32x4 accB[4];
            #pragma unroll
            for (int nt = 0; nt < 4; ++nt) { accA[nt] = zf; accB[nt] = zf; }
            const float* efr = ef + (size_t)(e0t + arow) * EIN;
            #pragma unroll
            for (int kt = 0; kt < 2; ++kt) {
                union { bf16x8 v; u16 u[8]; } a;
                #pragma unroll
                for (int p = 0; p < 4; ++p) {
                    const int k = kt*32 + kofs + 2*p;
                    float2 f = make_float2(0.f, 0.f);
                    if (k < 50) f = *(const float2*)&efr[k];   // exec-masked, 8B-aligned
                    a.u[2*p]   = f2bf(f.x);
                    a.u[2*p+1] = f2bf(f.y);
                }
                #pragma unroll
                for (int nt = 0; nt < 4; ++nt) {
                    accA[nt] = __builtin_amdgcn_mfma_f32_16x16x32_bf16(a.v, bAf[kt][nt], accA[nt], 0, 0, 0);
                    accB[nt] = __builtin_amdgcn_mfma_f32_16x16x32_bf16(a.v, bBf[kt][nt], accB[nt], 0, 0, 0);
                }
            }
            #pragma unroll
            for (int r = 0; r < 4; ++r) rd_[r] = sdst[rbase + r];   // capture pre-(b)
            #pragma unroll
            for (int nt = 0; nt < 4; ++nt) {
                const int c = nt*16 + frow;
                if (c < 50) {
                    const float bb = sb[HH + c];
                    #pragma unroll
                    for (int r = 0; r < 4; ++r) {
                        sint[(rbase + r)*192 + swz(rbase + r, 128 + c)] =
                            f2bf(fmaxf(accB[nt][r] + bb, 0.f));
                    }
                }
            }
        }
        __syncthreads();   // (b) sint fully written

        // ---- deferred e2n atomics: drain overlaps stage-2 + next gather ----
        #pragma unroll
        for (int nt = 0; nt < 4; ++nt) {
            const int c = nt*16 + frow;
            if (c < 50) {
                const float ba = sb[c];
                #pragma unroll
                for (int r = 0; r < 4; ++r) {
                    atomicAdd(&edge_node_acc[(size_t)rd_[r]*HH + c],
                              fmaxf(accA[nt][r] + ba, 0.f));
                }
            }
        }

        // ---- stage 2: new_edge = relu(sint @ wUt + bU) ----
        {
            f32x4 zf = {0.f, 0.f, 0.f, 0.f};
            f32x4 acc[4];
            #pragma unroll
            for (int nt = 0; nt < 4; ++nt) acc[nt] = zf;
            #pragma unroll
            for (int kt = 0; kt < 6; ++kt) {
                bf16x8 a = *(const bf16x8*)&sint[arow*192 + swz(arow, kt*32 + kofs)];
                #pragma unroll
                for (int nt = 0; nt < 4; ++nt) {
                    const int nrow = nt*16 + frow;
                    bf16x8 b = *(const bf16x8*)&wUt[nrow*192 + swz(nrow, kt*32 + kofs)];
                    acc[nt] = __builtin_amdgcn_mfma_f32_16x16x32_bf16(a, b, acc[nt], 0, 0, 0);
                }
            }
            #pragma unroll
            for (int nt = 0; nt < 4; ++nt) {
                const int c = nt*16 + frow;
                if (c < 50) {
                    const float bu = sb[2*HH + c];
                    #pragma unroll
                    for (int r = 0; r < 4; ++r) {
                        const int row = rbase + r;
                        out_edge[(size_t)(e0t + row)*HH + c] = fmaxf(acc[nt][r] + bu, 0.f);
                    }
                }
            }
        }
    }
}

// ---------------------------------------------------------------------------
// Kernel C (round-6 verified, staging mappings reverted): fallback path.
// ---------------------------------------------------------------------------
__global__ __launch_bounds__(256, 2) void k_node_upd(
    const float* __restrict__ nf,
    const float* __restrict__ w_n2n, const float* __restrict__ b_n2n,
    const float* __restrict__ wU, const float* __restrict__ bU,
    float* __restrict__ node_out)
{
    __shared__ __align__(16) u16 smem[64*128 + 64*128];  // 32768 B
    __shared__ __align__(16) u16 swu[64 * 192];          // 24576 B
    __shared__ float sb[128];

    const int tid = threadIdx.x;
    const int n0  = blockIdx.x * 64;

    const float4* nf4 = (const float4*)nf;
    for (int i = tid; i < 64 * 32; i += 256) {
        const int row = i >> 5, k4 = (i & 31) << 2;
        float4 v = make_float4(0.f, 0.f, 0.f, 0.f);
        const int gr = n0 + row;
        if (gr < V_N) v = nf4[(size_t)gr * 32 + (k4 >> 2)];
        ushort4 p;
        p.x = f2bf(v.x); p.y = f2bf(v.y); p.z = f2bf(v.z); p.w = f2bf(v.w);
        *(ushort4*)&smem[(row << 7) + swz(row, k4)] = p;
    }
    for (int i = tid; i < 64 * 128; i += 256) {
        const int n = i >> 7, k = i & 127;
        const float v = (n < 50) ? w_n2n[k*50 + n] : 0.f;
        smem[8192 + (n << 7) + swz(n, k)] = f2bf(v);
    }
    for (int i = tid; i < 64 * 192; i += 256) {
        const int n = i / 192, kk = i - n*192;
        float v = 0.f;
        if (n < 50) {
            if (kk < 100)      v = wU[kk*50 + n];
            else if (kk < 150) v = wU[(kk - 50)*50 + n];
        }
        swu[n*192 + swz(n, kk)] = f2bf(v);
    }
    if (tid < 128) {
        float v = 0.f;
        if (tid < 50) v = b_n2n[tid];
        else if (tid >= 64 && tid < 114) v = bU[tid - 64];
        sb[tid] = v;
    }
    __syncthreads();

    const int lane = tid & 63, wv = tid >> 6;
    const int frow = lane & 15;
    const int kofs = (lane >> 4) << 3;
    const int rbase = wv*16 + ((lane >> 4) << 2);
    const int arow  = wv*16 + frow;

    f32x4 zf = {0.f, 0.f, 0.f, 0.f};

    f32x4 accB[4];
    #pragma unroll
    for (int nt = 0; nt < 4; ++nt) accB[nt] = zf;
    #pragma unroll
    for (int kt = 0; kt < 4; ++kt) {
        bf16x8 a = *(const bf16x8*)&smem[(arow << 7) + swz(arow, kt*32 + kofs)];
        #pragma unroll
        for (int nt = 0; nt < 4; ++nt) {
            const int nrow = nt*16 + frow;
            bf16x8 b = *(const bf16x8*)&smem[8192 + (nrow << 7) + swz(nrow, kt*32 + kofs)];
            accB[nt] = __builtin_amdgcn_mfma_f32_16x16x32_bf16(a, b, accB[nt], 0, 0, 0);
        }
    }
    __syncthreads();

    #pragma unroll
    for (int nt = 0; nt < 4; ++nt) {
        const int g = nt*16 + frow;
        if (g < 50) {
            const float bias = sb[g];
            #pragma unroll
            for (int r = 0; r < 4; ++r) {
                const int row = rbase + r;
                smem[row*192 + swz(row, g)] = f2bf(fmaxf(accB[nt][r] + bias, 0.f));
            }
        }
    }
    for (int i = tid; i < 4096; i += 256) {
        const int row = i >> 6, q = i & 63;
        if (q < 50) {
            float en = 0.f;
            const int gr = n0 + row;
            if (gr < V_N) en = node_out[(size_t)gr*HH + q];
            const u16 hi = f2bf(en);
            const u16 lo = f2bf(en - bf2f(hi));
            smem[row*192 + swz(row,  50 + q)] = hi;
            smem[row*192 + swz(row, 100 + q)] = lo;
        }
    }
    for (int i = tid; i < 4096; i += 256) {
        const int row = i >> 6, q = i & 63;
        if (q < 42) smem[row*192 + swz(row, 150 + q)] = 0;
    }
    __syncthreads();

    f32x4 accC[4];
    #pragma unroll
    for (int nt = 0; nt < 4; ++nt) accC[nt] = zf;
    #pragma unroll
    for (int kt = 0; kt < 6; ++kt) {
        bf16x8 a = *(const bf16x8*)&smem[arow*192 + swz(arow, kt*32 + kofs)];
        #pragma unroll
        for (int nt = 0; nt < 4; ++nt) {
            const int nrow = nt*16 + frow;
            bf16x8 b = *(const bf16x8*)&swu[nrow*192 + swz(nrow, kt*32 + kofs)];
            accC[nt] = __builtin_amdgcn_mfma_f32_16x16x32_bf16(a, b, accC[nt], 0, 0, 0);
        }
    }
    #pragma unroll
    for (int nt = 0; nt < 4; ++nt) {
        const int g = nt*16 + frow;
        if (g < 50) {
            const float bias = sb[64 + g];
            #pragma unroll
            for (int r = 0; r < 4; ++r) {
                const int gr = n0 + rbase + r;
                if (gr < V_N)
                    node_out[(size_t)gr*HH + g] = fmaxf(accC[nt][r] + bias, 0.f);
            }
        }
    }
}

// ---------------------------------------------------------------------------
// Kernel C-fused: phase-C only; nn read from ws (bf16). LDS 49.4 KB -> 3/CU.
// ---------------------------------------------------------------------------
__global__ __launch_bounds__(256, 3) void k_node3(
    const u16* __restrict__ nn,
    const float* __restrict__ wU, const float* __restrict__ bU,
    float* __restrict__ node_out)
{
    __shared__ __align__(16) u16 smem[64 * 192];   // concat tile
    __shared__ __align__(16) u16 swu [64 * 192];
    __shared__ float sb[64];

    const int tid = threadIdx.x;
    const int n0  = blockIdx.x * 64;

    for (int i = tid; i < 64 * 192; i += 256) {    // kk fast: conflict-free
        const int n = i / 192, kk = i - n*192;
        float v = 0.f;
        if (n < 50) {
            if (kk < 100)      v = wU[kk*50 + n];
            else if (kk < 150) v = wU[(kk - 50)*50 + n];
        }
        swu[n*192 + swz(n, kk)] = f2bf(v);
    }
    if (tid < 50) sb[tid] = bU[tid];
    // concat: nn -> k' 0..49 (coalesced u16 reads)
    for (int i = tid; i < 4096; i += 256) {
        const int row = i >> 6, q = i & 63;
        if (q < 50) {
            const int gr = n0 + row;
            const u16 v = (gr < V_N) ? nn[(size_t)gr*HH + q] : (u16)0;
            smem[row*192 + swz(row, q)] = v;
        }
    }
    // en hi/lo -> k' 50..99 / 100..149
    for (int i = tid; i < 4096; i += 256) {
        const int row = i >> 6, q = i & 63;
        if (q < 50) {
            float en = 0.f;
            const int gr = n0 + row;
            if (gr < V_N) en = node_out[(size_t)gr*HH + q];
            const u16 hi = f2bf(en);
            const u16 lo = f2bf(en - bf2f(hi));
            smem[row*192 + swz(row,  50 + q)] = hi;
            smem[row*192 + swz(row, 100 + q)] = lo;
        }
    }
    // zeros -> k' 150..191
    for (int i = tid; i < 4096; i += 256) {
        const int row = i >> 6, q = i & 63;
        if (q < 42) smem[row*192 + swz(row, 150 + q)] = 0;
    }
    __syncthreads();

    const int lane = tid & 63, wv = tid >> 6;
    const int frow = lane & 15;
    const int kofs = (lane >> 4) << 3;
    const int rbase = wv*16 + ((lane >> 4) << 2);
    const int arow  = wv*16 + frow;

    f32x4 zf = {0.f, 0.f, 0.f, 0.f};
    f32x4 acc[4];
    #pragma unroll
    for (int nt = 0; nt < 4; ++nt) acc[nt] = zf;
    #pragma unroll
    for (int kt = 0; kt < 6; ++kt) {
        bf16x8 a = *(const bf16x8*)&smem[arow*192 + swz(arow, kt*32 + kofs)];
        #pragma unroll
        for (int nt = 0; nt < 4; ++nt) {
            const int nrow = nt*16 + frow;
            bf16x8 b = *(const bf16x8*)&swu[nrow*192 + swz(nrow, kt*32 + kofs)];
            acc[nt] = __builtin_amdgcn_mfma_f32_16x16x32_bf16(a, b, acc[nt], 0, 0, 0);
        }
    }
    #pragma unroll
    for (int nt = 0; nt < 4; ++nt) {
        const int g = nt*16 + frow;
        if (g < 50) {
            const float bias = sb[g];
            #pragma unroll
            for (int r = 0; r < 4; ++r) {
                const int gr = n0 + rbase + r;
                if (gr < V_N)
                    node_out[(size_t)gr*HH + g] = fmaxf(acc[nt][r] + bias, 0.f);
            }
        }
    }
}

extern "C" void kernel_launch(void* const* d_in, const int* in_sizes, int n_in,
                              void* d_out, int out_size, void* d_ws, size_t ws_size,
                              hipStream_t stream) {
    const float* nf    = (const float*)d_in[0];
    const float* ef    = (const float*)d_in[1];
    const int*   src   = (const int*)d_in[2];
    const int*   dst   = (const int*)d_in[3];
    const float* w_n2n = (const float*)d_in[4];  const float* b_n2n = (const float*)d_in[5];
    const float* w_e2n = (const float*)d_in[6];  const float* b_e2n = (const float*)d_in[7];
    const float* w_updn= (const float*)d_in[8];  const float* b_updn= (const float*)d_in[9];
    const float* w_l   = (const float*)d_in[10]; const float* b_l   = (const float*)d_in[11];
    const float* w_r   = (const float*)d_in[12]; const float* b_r   = (const float*)d_in[13];
    const float* w_e2e = (const float*)d_in[14]; const float* b_e2e = (const float*)d_in[15];
    const float* w_upde= (const float*)d_in[16]; const float* b_upde= (const float*)d_in[17];

    // ws layout: [0,10MB) left bf16, [10,20MB) right bf16, [20,30MB) nn bf16
    // (nn only if ws_size permits; else fallback path recomputes phase B).
    char* ws = (char*)d_ws;
    u16* left  = (u16*)ws;
    u16* right = (u16*)(ws + 10000000);
    u16* nn    = (u16*)(ws + 20000000);
    const bool fused = (ws_size >= 30000000);

    float* out_node = (float*)d_out;   // doubles as edge_node fp32 accumulator
    float* out_edge = out_node + (size_t)V_N * HH;

    hipMemsetAsync(out_node, 0, (size_t)V_N * HH * sizeof(float), stream);

    if (fused) {
        k_lr3<<<NBLK, 256, 0, stream>>>(nf, w_l, b_l, w_r, b_r, w_n2n, b_n2n,
                                        left, right, nn);
    } else {
        k_lr<<<NBLK, 256, 0, stream>>>(nf, w_l, b_l, w_r, b_r, left, right);
    }

    k_edge<<<E_N/(64*TPB), 256, 0, stream>>>(
        ef, src, dst, w_e2n, b_e2n, w_e2e, b_e2e, w_upde, b_upde,
        left, right, out_node, out_edge);

    if (fused) {
        k_node3<<<NBLK, 256, 0, stream>>>(nn, w_updn, b_updn, out_node);
    } else {
        k_node_upd<<<NBLK, 256, 0, stream>>>(nf, w_n2n, b_n2n, w_updn, b_updn,
                                             out_node);
    }
}